// Round 6
// baseline (221.428 us; speedup 1.0000x reference)
//
#include <hip/hip_runtime.h>

#define N_NODES 50000
#define IN_CH   128
#define HID_CH  256
#define OUT_CH  128
#define SRC_HALF (N_NODES / 2)

#define NB    196          // buckets: dst>>8
#define NWG   256          // count/scatter workgroups
#define NBNW  (NB * NWG)   // 50176

#define XBLK  3125         // cvt-x blocks: 50000*128/8/256
#define WBLK  64           // cvt-weights blocks: 4*4096/256

typedef __attribute__((ext_vector_type(8))) short bf16x8;
typedef __attribute__((ext_vector_type(4))) float f32x4;
typedef __attribute__((ext_vector_type(2))) float f32x2;

__device__ __forceinline__ unsigned short f32_bf16_rne(float f) {
    unsigned u = __float_as_uint(f);
    unsigned r = u + 0x7fff + ((u >> 16) & 1);
    return (unsigned short)(r >> 16);
}

// convert 8 f32 at inp -> 8 bf16 at outp (16B store)
__device__ __forceinline__ void cvt8_io(const float* __restrict__ inp,
                                        unsigned short* __restrict__ outp)
{
    const float4* p = reinterpret_cast<const float4*>(inp);
    float4 a = p[0], b = p[1];
    alignas(16) unsigned short t[8] = {
        f32_bf16_rne(a.x), f32_bf16_rne(a.y), f32_bf16_rne(a.z), f32_bf16_rne(a.w),
        f32_bf16_rne(b.x), f32_bf16_rne(b.y), f32_bf16_rne(b.z), f32_bf16_rne(b.w)};
    *reinterpret_cast<int4*>(outp) = *reinterpret_cast<const int4*>(t);
}

// ---------------------------------------------------------------------------
// prep: role-dispatched fusion of {bucket-count (LDS hist), cvt x (bf16 into
// A1[:,128:256] + fp8), cvt W into concatenated GEMM layouts}.
// ---------------------------------------------------------------------------
__global__ __launch_bounds__(256) void prep_kernel(
    const int* __restrict__ src, const int* __restrict__ dst,
    int* __restrict__ counts, int E, int chunk,
    const float* __restrict__ x, unsigned short* __restrict__ A1,
    unsigned char* __restrict__ xb8,
    const float* __restrict__ W1l, const float* __restrict__ W1r,
    const float* __restrict__ W2l, const float* __restrict__ W2r,
    unsigned short* __restrict__ B1, unsigned short* __restrict__ W2cat)
{
    const int b = blockIdx.x;
    if (b < NWG) {
        __shared__ int h[NB];
        for (int i = threadIdx.x; i < NB; i += 256) h[i] = 0;
        __syncthreads();
        const int e0 = b * chunk;
        const int e1 = min(e0 + chunk, E);
        for (int e = e0 + threadIdx.x; e < e1; e += 256) {
            int s = src[e], d = dst[e];
            if ((unsigned)s < (unsigned)N_NODES && (unsigned)d < (unsigned)N_NODES)
                atomicAdd(&h[d >> 8], 1);
        }
        __syncthreads();
        for (int i = threadIdx.x; i < NB; i += 256)
            counts[i * NWG + b] = h[i];
    } else if (b < NWG + XBLK) {
        size_t j = (size_t)(b - NWG) * 256 + threadIdx.x;   // < 800000 exactly
        const float4* p = reinterpret_cast<const float4*>(x) + 2 * j;
        float4 a = p[0], bb = p[1];
        alignas(16) unsigned short t[8] = {
            f32_bf16_rne(a.x),  f32_bf16_rne(a.y),  f32_bf16_rne(a.z),  f32_bf16_rne(a.w),
            f32_bf16_rne(bb.x), f32_bf16_rne(bb.y), f32_bf16_rne(bb.z), f32_bf16_rne(bb.w)};
        const size_t node = j >> 4, chunk16 = j & 15;       // 16 8-elem chunks/row
        *reinterpret_cast<int4*>(A1 + node * 256 + 128 + chunk16 * 8) =
            *reinterpret_cast<const int4*>(t);
        unsigned u0 = __builtin_amdgcn_cvt_pk_fp8_f32(a.x, a.y, 0, false);
        u0 = __builtin_amdgcn_cvt_pk_fp8_f32(a.z, a.w, u0, true);
        unsigned u1 = __builtin_amdgcn_cvt_pk_fp8_f32(bb.x, bb.y, 0, false);
        u1 = __builtin_amdgcn_cvt_pk_fp8_f32(bb.z, bb.w, u1, true);
        uint2 uv; uv.x = u0; uv.y = u1;
        *reinterpret_cast<uint2*>(xb8 + 8 * j) = uv;
    } else {
        int idx = (b - NWG - XBLK) * 256 + threadIdx.x;     // 0..16383
        int seg = idx >> 12, j = idx & 4095;
        if (seg == 0) {            // W1l [256][128] -> B1[row][0:128]
            int row = j >> 4, cb = (j & 15) * 8;
            cvt8_io(W1l + (size_t)j * 8, B1 + (size_t)row * 256 + cb);
        } else if (seg == 1) {     // W1r [256][128] -> B1[row][128:256]
            int row = j >> 4, cb = (j & 15) * 8;
            cvt8_io(W1r + (size_t)j * 8, B1 + (size_t)row * 256 + 128 + cb);
        } else if (seg == 2) {     // W2l [128][256] -> W2cat rows 0:128
            int row = j >> 5, cb = (j & 31) * 8;
            cvt8_io(W2l + (size_t)j * 8, W2cat + (size_t)row * 256 + cb);
        } else {                   // W2r [128][256] -> W2cat rows 128:256
            int row = j >> 5, cb = (j & 31) * 8;
            cvt8_io(W2r + (size_t)j * 8, W2cat + (size_t)(128 + row) * 256 + cb);
        }
    }
}

// ---------------------------------------------------------------------------
// One-kernel scan over counts[NBNW] (bucket-major [bucket][wg]).
// ---------------------------------------------------------------------------
__global__ __launch_bounds__(256) void scan_kernel(
    const int* __restrict__ counts, int* __restrict__ S)
{
    __shared__ int red[256];
    const int t = threadIdx.x;
    const int b = blockIdx.x;
    const int lim = b * NWG;
    int partial = 0;
    for (int i = t; i < lim; i += 256) partial += counts[i];
    red[t] = partial;
    __syncthreads();
    for (int off = 128; off >= 1; off >>= 1) {
        if (t < off) red[t] += red[t + off];
        __syncthreads();
    }
    const int base_b = red[0];
    __syncthreads();
    const int v = counts[b * NWG + t];      // NWG == 256 == blockDim
    red[t] = v;
    __syncthreads();
    for (int off = 1; off < 256; off <<= 1) {
        int u = (t >= off) ? red[t - off] : 0;
        __syncthreads();
        if (t >= off) red[t] += u;
        __syncthreads();
    }
    S[b * NWG + t] = base_b + red[t] - v;   // exclusive prefix
    if (b == NB - 1 && t == 255) S[NBNW] = base_b + red[255];
}

// ---------------------------------------------------------------------------
// Scatter packed (src<<8 | dst&255) into (bucket,wg)-exclusive subregions.
// ---------------------------------------------------------------------------
__global__ __launch_bounds__(256) void bscatter_kernel(
    const int* __restrict__ src, const int* __restrict__ dst,
    const int* __restrict__ S, int* __restrict__ pairs, int E, int chunk)
{
    __shared__ int cur[NB];
    const int w = blockIdx.x;
    for (int i = threadIdx.x; i < NB; i += 256) cur[i] = S[i * NWG + w];
    __syncthreads();
    const int e0 = w * chunk;
    const int e1 = min(e0 + chunk, E);
    for (int e = e0 + threadIdx.x; e < e1; e += 256) {
        int s = src[e], d = dst[e];
        if ((unsigned)s < (unsigned)N_NODES && (unsigned)d < (unsigned)N_NODES) {
            int pos = atomicAdd(&cur[d >> 8], 1);
            pairs[pos] = (s << 8) | (d & 255);
        }
    }
}

// ---------------------------------------------------------------------------
// Per-bucket counting sort with 512 bins: key = (d&255)*2 + (src>=25000).
// Produces rowptr + splitp (start of high-src half) + colidx. The src-half
// split makes each agg pass's gather working set 3.2 MB -> L2-resident
// per XCD (4 MB), converting L3-latency misses into L2 hits.
// ---------------------------------------------------------------------------
__global__ __launch_bounds__(256) void bsort_kernel(
    const int* __restrict__ pairs, const int* __restrict__ S,
    int* __restrict__ rowptr, int* __restrict__ splitp, int* __restrict__ colidx)
{
    __shared__ int hcnt[512];
    __shared__ int hcur[512];
    __shared__ int ps[256];
    const int b = blockIdx.x;
    const int t = threadIdx.x;
    const int start = S[b * NWG];
    const int endv  = (b == NB - 1) ? S[NBNW] : S[(b + 1) * NWG];

    hcnt[t] = 0; hcnt[t + 256] = 0;
    __syncthreads();
    for (int e = start + t; e < endv; e += 256) {
        int p = pairs[e];
        int key = ((p & 255) << 1) | ((((unsigned)p >> 8) >= SRC_HALF) ? 1 : 0);
        atomicAdd(&hcnt[key], 1);
    }
    __syncthreads();
    const int a0 = hcnt[2 * t], a1 = hcnt[2 * t + 1];
    ps[t] = a0 + a1;
    __syncthreads();
    for (int off = 1; off < 256; off <<= 1) {
        int v = (t >= off) ? ps[t - off] : 0;
        __syncthreads();
        if (t >= off) ps[t] += v;
        __syncthreads();
    }
    const int base_excl = (t == 0) ? 0 : ps[t - 1];
    const int e0 = base_excl;        // exclusive prefix of bin 2t   (node t, low half)
    const int e1 = base_excl + a0;   // exclusive prefix of bin 2t+1 (node t, high half)
    hcur[2 * t] = e0; hcur[2 * t + 1] = e1;
    const int node = (b << 8) + t;
    if (node < N_NODES) { rowptr[node] = start + e0; splitp[node] = start + e1; }
    if (b == NB - 1 && t == 0) rowptr[N_NODES] = endv;
    __syncthreads();
    for (int e = start + t; e < endv; e += 256) {
        int p = pairs[e];
        int key = ((p & 255) << 1) | ((((unsigned)p >> 8) >= SRC_HALF) ? 1 : 0);
        int pos = atomicAdd(&hcur[key], 1);
        colidx[start + pos] = (unsigned)p >> 8;
    }
}

// ---------------------------------------------------------------------------
// fp8-payload aggregates: ONE 16-lane group per node (16 nodes per block),
// TWO source-half phases per node (L2-residency play, see bsort).
// ---------------------------------------------------------------------------
#define ACC8(v)                                                              \
    { f32x2 t0 = __builtin_amdgcn_cvt_pk_f32_fp8(v.x, false);                \
      f32x2 t1 = __builtin_amdgcn_cvt_pk_f32_fp8(v.x, true);                 \
      f32x2 t2 = __builtin_amdgcn_cvt_pk_f32_fp8(v.y, false);                \
      f32x2 t3 = __builtin_amdgcn_cvt_pk_f32_fp8(v.y, true);                 \
      acc[0] += t0.x; acc[1] += t0.y; acc[2] += t1.x; acc[3] += t1.y;        \
      acc[4] += t2.x; acc[5] += t2.y; acc[6] += t3.x; acc[7] += t3.y; }

#define LDROW(s, CH) (*reinterpret_cast<const uint2*>(feat + (size_t)(s) * (CH) + l8 * 8))

#define AGG_RANGE(CH, lo, hi)                                                   \
    for (int base = (lo); base < (hi); base += 16) {                            \
        const int cnt = min(16, (hi) - base);                                   \
        int ci = colidx[base + ((l8 < cnt) ? l8 : 0)];                          \
        int k = 0;                                                              \
        for (; k + 7 < cnt; k += 8) {                                           \
            int s0 = __shfl(ci, k, 16),     s1 = __shfl(ci, k + 1, 16);         \
            int s2 = __shfl(ci, k + 2, 16), s3 = __shfl(ci, k + 3, 16);         \
            int s4 = __shfl(ci, k + 4, 16), s5 = __shfl(ci, k + 5, 16);         \
            int s6 = __shfl(ci, k + 6, 16), s7 = __shfl(ci, k + 7, 16);         \
            uint2 v0 = LDROW(s0, CH); uint2 v1 = LDROW(s1, CH);                 \
            uint2 v2 = LDROW(s2, CH); uint2 v3 = LDROW(s3, CH);                 \
            uint2 v4 = LDROW(s4, CH); uint2 v5 = LDROW(s5, CH);                 \
            uint2 v6 = LDROW(s6, CH); uint2 v7 = LDROW(s7, CH);                 \
            ACC8(v0) ACC8(v1) ACC8(v2) ACC8(v3)                                 \
            ACC8(v4) ACC8(v5) ACC8(v6) ACC8(v7)                                 \
        }                                                                       \
        for (; k + 3 < cnt; k += 4) {                                           \
            int s0 = __shfl(ci, k, 16),     s1 = __shfl(ci, k + 1, 16);         \
            int s2 = __shfl(ci, k + 2, 16), s3 = __shfl(ci, k + 3, 16);         \
            uint2 v0 = LDROW(s0, CH); uint2 v1 = LDROW(s1, CH);                 \
            uint2 v2 = LDROW(s2, CH); uint2 v3 = LDROW(s3, CH);                 \
            ACC8(v0) ACC8(v1) ACC8(v2) ACC8(v3)                                 \
        }                                                                       \
        for (; k < cnt; ++k) {                                                  \
            int s0 = __shfl(ci, k, 16);                                         \
            uint2 v0 = LDROW(s0, CH);                                           \
            ACC8(v0)                                                            \
        }                                                                       \
    }

#define AGG_BODY(CH)                                                            \
    const int node = blockIdx.x * 16 + (threadIdx.x >> 4);                      \
    if (node >= N_NODES) return;                                                \
    const int l8 = threadIdx.x & 15;                                            \
    const int beg = rowptr[node], end = rowptr[node + 1];                       \
    const int mid = splitp[node];                                               \
    const int len = end - beg;                                                  \
    float acc[8] = {};                                                          \
    AGG_RANGE(CH, beg, mid)                                                     \
    AGG_RANGE(CH, mid, end)                                                     \
    const float sc = 1.0f / fmaxf((float)len, 1.0f);

// agg1 writes mean into A1[:,0:128] (cols 128:256 hold bf16 x from prep)
__global__ __launch_bounds__(256) void agg1_kernel(
    const unsigned char* __restrict__ feat, const int* __restrict__ rowptr,
    const int* __restrict__ splitp, const int* __restrict__ colidx,
    unsigned short* __restrict__ A1)
{
    AGG_BODY(IN_CH)
    alignas(16) unsigned short t[8];
#pragma unroll
    for (int k = 0; k < 8; ++k) t[k] = f32_bf16_rne(acc[k] * sc);
    *reinterpret_cast<int4*>(A1 + (size_t)node * 256 + l8 * 8) =
        *reinterpret_cast<const int4*>(t);
}

// agg2: sole writer of out: out[n] = mean_p[n] + hr[n] + b2l
__global__ __launch_bounds__(256) void agg2_kernel(
    const unsigned char* __restrict__ feat, const int* __restrict__ rowptr,
    const int* __restrict__ splitp, const int* __restrict__ colidx,
    const unsigned short* __restrict__ hrb,
    const float* __restrict__ b2l, float* __restrict__ out)
{
    AGG_BODY(OUT_CH)
    const int4 hv = *reinterpret_cast<const int4*>(hrb + (size_t)node * OUT_CH + l8 * 8);
    const unsigned short* hs = reinterpret_cast<const unsigned short*>(&hv);
    float4 b0 = *reinterpret_cast<const float4*>(b2l + l8 * 8);
    float4 b1 = *reinterpret_cast<const float4*>(b2l + l8 * 8 + 4);
    float4 o0, o1;
    o0.x = acc[0] * sc + __uint_as_float((unsigned)hs[0] << 16) + b0.x;
    o0.y = acc[1] * sc + __uint_as_float((unsigned)hs[1] << 16) + b0.y;
    o0.z = acc[2] * sc + __uint_as_float((unsigned)hs[2] << 16) + b0.z;
    o0.w = acc[3] * sc + __uint_as_float((unsigned)hs[3] << 16) + b0.w;
    o1.x = acc[4] * sc + __uint_as_float((unsigned)hs[4] << 16) + b1.x;
    o1.y = acc[5] * sc + __uint_as_float((unsigned)hs[5] << 16) + b1.y;
    o1.z = acc[6] * sc + __uint_as_float((unsigned)hs[6] << 16) + b1.z;
    o1.w = acc[7] * sc + __uint_as_float((unsigned)hs[7] << 16) + b1.w;
    float* o = out + (size_t)node * OUT_CH + l8 * 8;
    reinterpret_cast<float4*>(o)[0] = o0;
    reinterpret_cast<float4*>(o)[1] = o1;
}

// ---------------------------------------------------------------------------
// MFMA GEMMs — 128x256 block tile, 8 waves (2M x 4N), 512 threads.
// ---------------------------------------------------------------------------
template <int NIT>
__device__ __forceinline__ void stage8(
    const unsigned short* __restrict__ g, int ldg, int rowBase, int maxRow,
    int kBase, unsigned short* __restrict__ s, int tid)
{
    const int wave = tid >> 6;          // 0..7, wave-uniform
    const int lane = tid & 63;
    const int r_in = lane >> 3;         // 0..7 within 8-row group
    const int c_g  = (lane & 7) ^ r_in; // chunk destined for this lane's LDS slot
#pragma unroll
    for (int it = 0; it < NIT; ++it) {
        const int rowBlk = it * 64 + wave * 8;        // 8 waves x 8 rows = 64/iter
        int row = rowBase + rowBlk + r_in;
        if (row >= maxRow) row = maxRow - 1;          // clamp; epilogue guards stores
        const unsigned short* gp = g + (size_t)row * ldg + kBase + c_g * 8;
        unsigned short* lp = s + rowBlk * 64;         // wave-uniform; HW adds lane*16
        __builtin_amdgcn_global_load_lds(
            (const __attribute__((address_space(1))) unsigned int*)gp,
            (__attribute__((address_space(3))) unsigned int*)lp,
            16, 0, 0);
    }
}

__device__ __forceinline__ const bf16x8* frag_ptr(
    const unsigned short* __restrict__ s, int rr, int c)
{
    return reinterpret_cast<const bf16x8*>(s + rr * 64 + (((c ^ (rr & 7))) << 3));
}

__device__ __forceinline__ void mfma_tile(
    const unsigned short* __restrict__ As, const unsigned short* __restrict__ Bs,
    int wm, int wn, int l16, int quad, f32x4 acc[4][4])
{
#pragma unroll
    for (int k0 = 0; k0 < 64; k0 += 32) {
        const int c = (k0 >> 3) + quad;   // 16 B chunk index within row
        bf16x8 a[4], b[4];
#pragma unroll
        for (int i = 0; i < 4; ++i)
            a[i] = *frag_ptr(As, wm * 64 + i * 16 + l16, c);
#pragma unroll
        for (int j = 0; j < 4; ++j)
            b[j] = *frag_ptr(Bs, wn * 64 + j * 16 + l16, c);
#pragma unroll
        for (int i = 0; i < 4; ++i)
#pragma unroll
            for (int j = 0; j < 4; ++j)
                acc[i][j] = __builtin_amdgcn_mfma_f32_16x16x32_bf16(
                    b[j], a[i], acc[i][j], 0, 0, 0);   // swapped: D[chan][node]
    }
}

// gemm1: h = relu([mean|x] @ [W1l|W1r]^T + b1l)  — K=256, N=256, one pass
__global__ __launch_bounds__(512) void gemm1_mfma(
    const unsigned short* __restrict__ A1, const unsigned short* __restrict__ B1,
    const float* __restrict__ b1l, unsigned short* __restrict__ hb)
{
    __shared__ unsigned short As[128 * 64];
    __shared__ unsigned short Bs[256 * 64];
    const int tid = threadIdx.x;
    const int wid = tid >> 6, lane = tid & 63;
    const int wm = wid & 1, wn = wid >> 1;            // 2M x 4N
    const int l16 = lane & 15, quad = lane >> 4;
    const int rowBase = blockIdx.x * 128;

    f32x4 z = {0.f, 0.f, 0.f, 0.f};
    f32x4 acc[4][4];
#pragma unroll
    for (int i = 0; i < 4; ++i)
#pragma unroll
        for (int j = 0; j < 4; ++j) acc[i][j] = z;

#pragma unroll
    for (int kb = 0; kb < 256; kb += 64) {
        __syncthreads();
        stage8<2>(A1, 256, rowBase, N_NODES, kb, As, tid);
        stage8<4>(B1, 256, 0, HID_CH, kb, Bs, tid);
        __syncthreads();   // drains vmcnt(0): DMA complete before reads
        mfma_tile(As, Bs, wm, wn, l16, quad, acc);
    }

#pragma unroll
    for (int i = 0; i < 4; ++i) {
        int m = rowBase + wm * 64 + i * 16 + l16;
        if (m >= N_NODES) continue;
#pragma unroll
        for (int j = 0; j < 4; ++j) {
            int col = wn * 64 + j * 16 + quad * 4;    // 0..255
            float4 bv = *reinterpret_cast<const float4*>(b1l + col);
            alignas(8) unsigned short t[4];
            t[0] = f32_bf16_rne(fmaxf(acc[i][j][0] + bv.x, 0.0f));
            t[1] = f32_bf16_rne(fmaxf(acc[i][j][1] + bv.y, 0.0f));
            t[2] = f32_bf16_rne(fmaxf(acc[i][j][2] + bv.z, 0.0f));
            t[3] = f32_bf16_rne(fmaxf(acc[i][j][3] + bv.w, 0.0f));
            *reinterpret_cast<uint2*>(hb + (size_t)m * HID_CH + col) =
                *reinterpret_cast<const uint2*>(t);
        }
    }
}

// gemm2: one pass over hb produces p=h@W2l^T (fp8, cols 0:128) AND
// hr=h@W2r^T (bf16, cols 128:256) via row-concatenated W2cat.
__global__ __launch_bounds__(512) void gemm2_mfma(
    const unsigned short* __restrict__ hb, const unsigned short* __restrict__ W2cat,
    unsigned char* __restrict__ pb8, unsigned short* __restrict__ hrb)
{
    __shared__ unsigned short As[128 * 64];
    __shared__ unsigned short Bs[256 * 64];
    const int tid = threadIdx.x;
    const int wid = tid >> 6, lane = tid & 63;
    const int wm = wid & 1, wn = wid >> 1;
    const int l16 = lane & 15, quad = lane >> 4;
    const int rowBase = blockIdx.x * 128;

    f32x4 z = {0.f, 0.f, 0.f, 0.f};
    f32x4 acc[4][4];
#pragma unroll
    for (int i = 0; i < 4; ++i)
#pragma unroll
        for (int j = 0; j < 4; ++j) acc[i][j] = z;

#pragma unroll
    for (int kb = 0; kb < HID_CH; kb += 64) {
        __syncthreads();
        stage8<2>(hb, HID_CH, rowBase, N_NODES, kb, As, tid);
        stage8<4>(W2cat, HID_CH, 0, 256, kb, Bs, tid);
        __syncthreads();
        mfma_tile(As, Bs, wm, wn, l16, quad, acc);
    }

    if (wn < 2) {       // cols 0..127 -> fp8 payload p
#pragma unroll
        for (int i = 0; i < 4; ++i) {
            int m = rowBase + wm * 64 + i * 16 + l16;
            if (m >= N_NODES) continue;
#pragma unroll
            for (int j = 0; j < 4; ++j) {
                int col = wn * 64 + j * 16 + quad * 4;
                unsigned u = __builtin_amdgcn_cvt_pk_fp8_f32(
                    acc[i][j][0], acc[i][j][1], 0, false);
                u = __builtin_amdgcn_cvt_pk_fp8_f32(
                    acc[i][j][2], acc[i][j][3], u, true);
                *reinterpret_cast<unsigned*>(pb8 + (size_t)m * OUT_CH + col) = u;
            }
        }
    } else {            // cols 128..255 -> bf16 hr (bias deferred to agg2)
#pragma unroll
        for (int i = 0; i < 4; ++i) {
            int m = rowBase + wm * 64 + i * 16 + l16;
            if (m >= N_NODES) continue;
#pragma unroll
            for (int j = 0; j < 4; ++j) {
                int col = wn * 64 + j * 16 + quad * 4 - 128;
                alignas(8) unsigned short t[4];
                t[0] = f32_bf16_rne(acc[i][j][0]);
                t[1] = f32_bf16_rne(acc[i][j][1]);
                t[2] = f32_bf16_rne(acc[i][j][2]);
                t[3] = f32_bf16_rne(acc[i][j][3]);
                *reinterpret_cast<uint2*>(hrb + (size_t)m * OUT_CH + col) =
                    *reinterpret_cast<const uint2*>(t);
            }
        }
    }
}

extern "C" void kernel_launch(void* const* d_in, const int* in_sizes, int n_in,
                              void* d_out, int out_size, void* d_ws, size_t ws_size,
                              hipStream_t stream)
{
    const float* x   = (const float*)d_in[0];
    const int*   ei  = (const int*)d_in[1];
    const float* W1l = (const float*)d_in[2];
    const float* b1l = (const float*)d_in[3];
    const float* W1r = (const float*)d_in[4];
    const float* W2l = (const float*)d_in[5];
    const float* b2l = (const float*)d_in[6];
    const float* W2r = (const float*)d_in[7];

    const int E = in_sizes[1] / 2;
    const int* src = ei;
    const int* dst = ei + E;

    char* ws = (char*)d_ws;
    size_t off = 0;
    auto alloc = [&](size_t bytes) {
        void* p = ws + off;
        off += (bytes + 255) & ~(size_t)255;
        return p;
    };
    unsigned short* A1     = (unsigned short*)alloc((size_t)N_NODES * 256 * 2);
    unsigned char*  xb8    = (unsigned char*)alloc((size_t)N_NODES * IN_CH);
    unsigned short* hb     = (unsigned short*)alloc((size_t)N_NODES * HID_CH * 2);
    unsigned char*  pb8    = (unsigned char*)alloc((size_t)N_NODES * OUT_CH);
    unsigned short* hrb    = (unsigned short*)alloc((size_t)N_NODES * OUT_CH * 2);
    unsigned short* B1     = (unsigned short*)alloc((size_t)HID_CH * 256 * 2);
    unsigned short* W2cat  = (unsigned short*)alloc((size_t)256 * HID_CH * 2);
    int* counts = (int*)alloc((size_t)NBNW * 4);
    int* S      = (int*)alloc((size_t)(NBNW + 1) * 4);
    int* pairs  = (int*)alloc((size_t)E * 4);
    int* rowptr = (int*)alloc((size_t)(N_NODES + 1) * 4);
    int* splitp = (int*)alloc((size_t)N_NODES * 4);
    int* colidx = (int*)alloc((size_t)E * 4);
    float* out = (float*)d_out;

    const int chunk = (E + NWG - 1) / NWG;

    prep_kernel<<<NWG + XBLK + WBLK, 256, 0, stream>>>(
        src, dst, counts, E, chunk, x, A1, xb8,
        W1l, W1r, W2l, W2r, B1, W2cat);
    scan_kernel<<<NB, 256, 0, stream>>>(counts, S);
    bscatter_kernel<<<NWG, 256, 0, stream>>>(src, dst, S, pairs, E, chunk);
    bsort_kernel<<<NB, 256, 0, stream>>>(pairs, S, rowptr, splitp, colidx);

    const int aggBlocks = (N_NODES + 15) / 16;   // 3125
    const int mBlocks = (N_NODES + 127) / 128;   // 391

    agg1_kernel<<<aggBlocks, 256, 0, stream>>>(xb8, rowptr, splitp, colidx, A1);
    gemm1_mfma<<<mBlocks, 512, 0, stream>>>(A1, B1, b1l, hb);
    gemm2_mfma<<<mBlocks, 512, 0, stream>>>(hb, W2cat, pb8, hrb);
    agg2_kernel<<<aggBlocks, 256, 0, stream>>>(pb8, rowptr, splitp, colidx, hrb, b2l, out);
}

// Round 7
// 211.634 us; speedup vs baseline: 1.0463x; 1.0463x over previous
//
#include <hip/hip_runtime.h>

#define N_NODES 50000
#define IN_CH   128
#define HID_CH  256
#define OUT_CH  128

#define NB    196          // buckets: dst>>8
#define NWG   256          // count/scatter workgroups
#define NBNW  (NB * NWG)   // 50176

#define XBLK  3125         // cvt-x blocks: 50000*128/8/256
#define WBLK  64           // cvt-weights blocks: 4*4096/256

typedef __attribute__((ext_vector_type(8))) short bf16x8;
typedef __attribute__((ext_vector_type(4))) float f32x4;
typedef __attribute__((ext_vector_type(2))) float f32x2;

__device__ __forceinline__ unsigned short f32_bf16_rne(float f) {
    unsigned u = __float_as_uint(f);
    unsigned r = u + 0x7fff + ((u >> 16) & 1);
    return (unsigned short)(r >> 16);
}

// convert 8 f32 at inp -> 8 bf16 at outp (16B store)
__device__ __forceinline__ void cvt8_io(const float* __restrict__ inp,
                                        unsigned short* __restrict__ outp)
{
    const float4* p = reinterpret_cast<const float4*>(inp);
    float4 a = p[0], b = p[1];
    alignas(16) unsigned short t[8] = {
        f32_bf16_rne(a.x), f32_bf16_rne(a.y), f32_bf16_rne(a.z), f32_bf16_rne(a.w),
        f32_bf16_rne(b.x), f32_bf16_rne(b.y), f32_bf16_rne(b.z), f32_bf16_rne(b.w)};
    *reinterpret_cast<int4*>(outp) = *reinterpret_cast<const int4*>(t);
}

// ---------------------------------------------------------------------------
// prep: role-dispatched fusion of {bucket-count (LDS hist), cvt x (bf16 into
// A1[:,128:256] + fp8), cvt W into concatenated GEMM layouts}.
// ---------------------------------------------------------------------------
__global__ __launch_bounds__(256) void prep_kernel(
    const int* __restrict__ src, const int* __restrict__ dst,
    int* __restrict__ counts, int E, int chunk,
    const float* __restrict__ x, unsigned short* __restrict__ A1,
    unsigned char* __restrict__ xb8,
    const float* __restrict__ W1l, const float* __restrict__ W1r,
    const float* __restrict__ W2l, const float* __restrict__ W2r,
    unsigned short* __restrict__ B1, unsigned short* __restrict__ W2cat)
{
    const int b = blockIdx.x;
    if (b < NWG) {
        __shared__ int h[NB];
        for (int i = threadIdx.x; i < NB; i += 256) h[i] = 0;
        __syncthreads();
        const int e0 = b * chunk;
        const int e1 = min(e0 + chunk, E);
        for (int e = e0 + threadIdx.x; e < e1; e += 256) {
            int s = src[e], d = dst[e];
            if ((unsigned)s < (unsigned)N_NODES && (unsigned)d < (unsigned)N_NODES)
                atomicAdd(&h[d >> 8], 1);
        }
        __syncthreads();
        for (int i = threadIdx.x; i < NB; i += 256)
            counts[i * NWG + b] = h[i];
    } else if (b < NWG + XBLK) {
        size_t j = (size_t)(b - NWG) * 256 + threadIdx.x;   // < 800000 exactly
        const float4* p = reinterpret_cast<const float4*>(x) + 2 * j;
        float4 a = p[0], bb = p[1];
        alignas(16) unsigned short t[8] = {
            f32_bf16_rne(a.x),  f32_bf16_rne(a.y),  f32_bf16_rne(a.z),  f32_bf16_rne(a.w),
            f32_bf16_rne(bb.x), f32_bf16_rne(bb.y), f32_bf16_rne(bb.z), f32_bf16_rne(bb.w)};
        const size_t node = j >> 4, chunk16 = j & 15;       // 16 8-elem chunks/row
        *reinterpret_cast<int4*>(A1 + node * 256 + 128 + chunk16 * 8) =
            *reinterpret_cast<const int4*>(t);
        unsigned u0 = __builtin_amdgcn_cvt_pk_fp8_f32(a.x, a.y, 0, false);
        u0 = __builtin_amdgcn_cvt_pk_fp8_f32(a.z, a.w, u0, true);
        unsigned u1 = __builtin_amdgcn_cvt_pk_fp8_f32(bb.x, bb.y, 0, false);
        u1 = __builtin_amdgcn_cvt_pk_fp8_f32(bb.z, bb.w, u1, true);
        uint2 uv; uv.x = u0; uv.y = u1;
        *reinterpret_cast<uint2*>(xb8 + 8 * j) = uv;
    } else {
        int idx = (b - NWG - XBLK) * 256 + threadIdx.x;     // 0..16383
        int seg = idx >> 12, j = idx & 4095;
        if (seg == 0) {            // W1l [256][128] -> B1[row][0:128]
            int row = j >> 4, cb = (j & 15) * 8;
            cvt8_io(W1l + (size_t)j * 8, B1 + (size_t)row * 256 + cb);
        } else if (seg == 1) {     // W1r [256][128] -> B1[row][128:256]
            int row = j >> 4, cb = (j & 15) * 8;
            cvt8_io(W1r + (size_t)j * 8, B1 + (size_t)row * 256 + 128 + cb);
        } else if (seg == 2) {     // W2l [128][256] -> W2cat rows 0:128
            int row = j >> 5, cb = (j & 31) * 8;
            cvt8_io(W2l + (size_t)j * 8, W2cat + (size_t)row * 256 + cb);
        } else {                   // W2r [128][256] -> W2cat rows 128:256
            int row = j >> 5, cb = (j & 31) * 8;
            cvt8_io(W2r + (size_t)j * 8, W2cat + (size_t)(128 + row) * 256 + cb);
        }
    }
}

// ---------------------------------------------------------------------------
// One-kernel scan over counts[NBNW] (bucket-major [bucket][wg]).
// ---------------------------------------------------------------------------
__global__ __launch_bounds__(256) void scan_kernel(
    const int* __restrict__ counts, int* __restrict__ S)
{
    __shared__ int red[256];
    const int t = threadIdx.x;
    const int b = blockIdx.x;
    const int lim = b * NWG;
    int partial = 0;
    for (int i = t; i < lim; i += 256) partial += counts[i];
    red[t] = partial;
    __syncthreads();
    for (int off = 128; off >= 1; off >>= 1) {
        if (t < off) red[t] += red[t + off];
        __syncthreads();
    }
    const int base_b = red[0];
    __syncthreads();
    const int v = counts[b * NWG + t];      // NWG == 256 == blockDim
    red[t] = v;
    __syncthreads();
    for (int off = 1; off < 256; off <<= 1) {
        int u = (t >= off) ? red[t - off] : 0;
        __syncthreads();
        if (t >= off) red[t] += u;
        __syncthreads();
    }
    S[b * NWG + t] = base_b + red[t] - v;   // exclusive prefix
    if (b == NB - 1 && t == 255) S[NBNW] = base_b + red[255];
}

// ---------------------------------------------------------------------------
// Scatter packed (src<<8 | dst&255) into (bucket,wg)-exclusive subregions.
// ---------------------------------------------------------------------------
__global__ __launch_bounds__(256) void bscatter_kernel(
    const int* __restrict__ src, const int* __restrict__ dst,
    const int* __restrict__ S, int* __restrict__ pairs, int E, int chunk)
{
    __shared__ int cur[NB];
    const int w = blockIdx.x;
    for (int i = threadIdx.x; i < NB; i += 256) cur[i] = S[i * NWG + w];
    __syncthreads();
    const int e0 = w * chunk;
    const int e1 = min(e0 + chunk, E);
    for (int e = e0 + threadIdx.x; e < e1; e += 256) {
        int s = src[e], d = dst[e];
        if ((unsigned)s < (unsigned)N_NODES && (unsigned)d < (unsigned)N_NODES) {
            int pos = atomicAdd(&cur[d >> 8], 1);
            pairs[pos] = (s << 8) | (d & 255);
        }
    }
}

// ---------------------------------------------------------------------------
// Per-bucket local counting sort -> rowptr + colidx. LDS atomics only.
// (r6's src-half split reverted: L2-residency play was null -> gather floor
// is request-throughput, not latency.)
// ---------------------------------------------------------------------------
__global__ __launch_bounds__(256) void bsort_kernel(
    const int* __restrict__ pairs, const int* __restrict__ S,
    int* __restrict__ rowptr, int* __restrict__ colidx)
{
    __shared__ int hcnt[256];
    __shared__ int hcur[256];
    const int b = blockIdx.x;
    const int start = S[b * NWG];
    const int endv  = (b == NB - 1) ? S[NBNW] : S[(b + 1) * NWG];

    hcnt[threadIdx.x] = 0;
    __syncthreads();
    for (int e = start + threadIdx.x; e < endv; e += 256)
        atomicAdd(&hcnt[pairs[e] & 255], 1);
    __syncthreads();
    for (int off = 1; off < 256; off <<= 1) {
        int t = (threadIdx.x >= off) ? hcnt[threadIdx.x - off] : 0;
        __syncthreads();
        if (threadIdx.x >= off) hcnt[threadIdx.x] += t;
        __syncthreads();
    }
    int offv = (threadIdx.x == 0) ? 0 : hcnt[threadIdx.x - 1];
    hcur[threadIdx.x] = offv;
    int node = (b << 8) + threadIdx.x;
    if (node < N_NODES) rowptr[node] = start + offv;
    if (b == NB - 1 && threadIdx.x == 0) rowptr[N_NODES] = endv;
    __syncthreads();
    for (int e = start + threadIdx.x; e < endv; e += 256) {
        int p = pairs[e];
        int pos = atomicAdd(&hcur[p & 255], 1);
        colidx[start + pos] = (unsigned)p >> 8;
    }
}

// ---------------------------------------------------------------------------
// fp8-payload aggregates: ONE 16-lane group per node (16 nodes per block).
// ---------------------------------------------------------------------------
#define ACC8(v)                                                              \
    { f32x2 t0 = __builtin_amdgcn_cvt_pk_f32_fp8(v.x, false);                \
      f32x2 t1 = __builtin_amdgcn_cvt_pk_f32_fp8(v.x, true);                 \
      f32x2 t2 = __builtin_amdgcn_cvt_pk_f32_fp8(v.y, false);                \
      f32x2 t3 = __builtin_amdgcn_cvt_pk_f32_fp8(v.y, true);                 \
      acc[0] += t0.x; acc[1] += t0.y; acc[2] += t1.x; acc[3] += t1.y;        \
      acc[4] += t2.x; acc[5] += t2.y; acc[6] += t3.x; acc[7] += t3.y; }

#define LDROW(s, CH) (*reinterpret_cast<const uint2*>(feat + (size_t)(s) * (CH) + l8 * 8))

#define AGG_BODY(CH)                                                            \
    const int node = blockIdx.x * 16 + (threadIdx.x >> 4);                      \
    if (node >= N_NODES) return;                                                \
    const int l8 = threadIdx.x & 15;                                            \
    const int beg = rowptr[node], end = rowptr[node + 1];                       \
    const int len = end - beg;                                                  \
    float acc[8] = {};                                                          \
    for (int base = beg; base < end; base += 16) {                              \
        const int cnt = min(16, end - base);                                    \
        int ci = colidx[base + ((l8 < cnt) ? l8 : 0)];                          \
        int k = 0;                                                              \
        for (; k + 7 < cnt; k += 8) {                                           \
            int s0 = __shfl(ci, k, 16),     s1 = __shfl(ci, k + 1, 16);         \
            int s2 = __shfl(ci, k + 2, 16), s3 = __shfl(ci, k + 3, 16);         \
            int s4 = __shfl(ci, k + 4, 16), s5 = __shfl(ci, k + 5, 16);         \
            int s6 = __shfl(ci, k + 6, 16), s7 = __shfl(ci, k + 7, 16);         \
            uint2 v0 = LDROW(s0, CH); uint2 v1 = LDROW(s1, CH);                 \
            uint2 v2 = LDROW(s2, CH); uint2 v3 = LDROW(s3, CH);                 \
            uint2 v4 = LDROW(s4, CH); uint2 v5 = LDROW(s5, CH);                 \
            uint2 v6 = LDROW(s6, CH); uint2 v7 = LDROW(s7, CH);                 \
            ACC8(v0) ACC8(v1) ACC8(v2) ACC8(v3)                                 \
            ACC8(v4) ACC8(v5) ACC8(v6) ACC8(v7)                                 \
        }                                                                       \
        for (; k + 3 < cnt; k += 4) {                                           \
            int s0 = __shfl(ci, k, 16),     s1 = __shfl(ci, k + 1, 16);         \
            int s2 = __shfl(ci, k + 2, 16), s3 = __shfl(ci, k + 3, 16);         \
            uint2 v0 = LDROW(s0, CH); uint2 v1 = LDROW(s1, CH);                 \
            uint2 v2 = LDROW(s2, CH); uint2 v3 = LDROW(s3, CH);                 \
            ACC8(v0) ACC8(v1) ACC8(v2) ACC8(v3)                                 \
        }                                                                       \
        for (; k < cnt; ++k) {                                                  \
            int s0 = __shfl(ci, k, 16);                                         \
            uint2 v0 = LDROW(s0, CH);                                           \
            ACC8(v0)                                                            \
        }                                                                       \
    }                                                                           \
    const float sc = 1.0f / fmaxf((float)len, 1.0f);

// agg1 writes mean into A1[:,0:128] (cols 128:256 hold bf16 x from prep)
__global__ __launch_bounds__(256) void agg1_kernel(
    const unsigned char* __restrict__ feat, const int* __restrict__ rowptr,
    const int* __restrict__ colidx, unsigned short* __restrict__ A1)
{
    AGG_BODY(IN_CH)
    alignas(16) unsigned short t[8];
#pragma unroll
    for (int k = 0; k < 8; ++k) t[k] = f32_bf16_rne(acc[k] * sc);
    *reinterpret_cast<int4*>(A1 + (size_t)node * 256 + l8 * 8) =
        *reinterpret_cast<const int4*>(t);
}

// agg2: sole writer of out: out[n] = mean_p[n] + hr[n] + b2l
__global__ __launch_bounds__(256) void agg2_kernel(
    const unsigned char* __restrict__ feat, const int* __restrict__ rowptr,
    const int* __restrict__ colidx, const unsigned short* __restrict__ hrb,
    const float* __restrict__ b2l, float* __restrict__ out)
{
    AGG_BODY(OUT_CH)
    const int4 hv = *reinterpret_cast<const int4*>(hrb + (size_t)node * OUT_CH + l8 * 8);
    const unsigned short* hs = reinterpret_cast<const unsigned short*>(&hv);
    float4 b0 = *reinterpret_cast<const float4*>(b2l + l8 * 8);
    float4 b1 = *reinterpret_cast<const float4*>(b2l + l8 * 8 + 4);
    float4 o0, o1;
    o0.x = acc[0] * sc + __uint_as_float((unsigned)hs[0] << 16) + b0.x;
    o0.y = acc[1] * sc + __uint_as_float((unsigned)hs[1] << 16) + b0.y;
    o0.z = acc[2] * sc + __uint_as_float((unsigned)hs[2] << 16) + b0.z;
    o0.w = acc[3] * sc + __uint_as_float((unsigned)hs[3] << 16) + b0.w;
    o1.x = acc[4] * sc + __uint_as_float((unsigned)hs[4] << 16) + b1.x;
    o1.y = acc[5] * sc + __uint_as_float((unsigned)hs[5] << 16) + b1.y;
    o1.z = acc[6] * sc + __uint_as_float((unsigned)hs[6] << 16) + b1.z;
    o1.w = acc[7] * sc + __uint_as_float((unsigned)hs[7] << 16) + b1.w;
    float* o = out + (size_t)node * OUT_CH + l8 * 8;
    reinterpret_cast<float4*>(o)[0] = o0;
    reinterpret_cast<float4*>(o)[1] = o1;
}

// ---------------------------------------------------------------------------
// FUSED MFMA GEMM: block i computes the 128x256 h-tile (layer-1 + bias +
// relu, bf16) entirely in LDS, then immediately runs layer 2 from it.
// Eliminates the hb global round-trip (51.2 MB) and one dispatch.
// h's bf16 rounding is identical to the old global-store path -> bit-identical.
// LDS: As 16 KB + Bs 32 KB (reused by phase 2) + Hs 64 KB = 112 KB.
// Hs chunk-XOR swizzle: phys_chunk = grp*8 + (local_chunk ^ (row&7)) keeps
// 16-row ds_read_b128 columns spread over 8 bank slots (2-way = free).
// ---------------------------------------------------------------------------
template <int NIT>
__device__ __forceinline__ void stage8(
    const unsigned short* __restrict__ g, int ldg, int rowBase, int maxRow,
    int kBase, unsigned short* __restrict__ s, int tid)
{
    const int wave = tid >> 6;          // 0..7, wave-uniform
    const int lane = tid & 63;
    const int r_in = lane >> 3;         // 0..7 within 8-row group
    const int c_g  = (lane & 7) ^ r_in; // chunk destined for this lane's LDS slot
#pragma unroll
    for (int it = 0; it < NIT; ++it) {
        const int rowBlk = it * 64 + wave * 8;        // 8 waves x 8 rows = 64/iter
        int row = rowBase + rowBlk + r_in;
        if (row >= maxRow) row = maxRow - 1;          // clamp; epilogue guards stores
        const unsigned short* gp = g + (size_t)row * ldg + kBase + c_g * 8;
        unsigned short* lp = s + rowBlk * 64;         // wave-uniform; HW adds lane*16
        __builtin_amdgcn_global_load_lds(
            (const __attribute__((address_space(1))) unsigned int*)gp,
            (__attribute__((address_space(3))) unsigned int*)lp,
            16, 0, 0);
    }
}

__device__ __forceinline__ const bf16x8* frag_ptr(
    const unsigned short* __restrict__ s, int rr, int c)
{
    return reinterpret_cast<const bf16x8*>(s + rr * 64 + (((c ^ (rr & 7))) << 3));
}

// Hs fragment: row-stride 256 shorts, chunk group kbc (= kb>>3), logical
// chunk c within the 8-chunk group, XOR-swizzled by row.
__device__ __forceinline__ const bf16x8* hfrag_ptr(
    const unsigned short* __restrict__ s, int rr, int kbc, int c)
{
    return reinterpret_cast<const bf16x8*>(
        s + rr * 256 + ((kbc + (c ^ (rr & 7))) << 3));
}

__device__ __forceinline__ void mfma_tile(
    const unsigned short* __restrict__ As, const unsigned short* __restrict__ Bs,
    int wm, int wn, int l16, int quad, f32x4 acc[4][4])
{
#pragma unroll
    for (int k0 = 0; k0 < 64; k0 += 32) {
        const int c = (k0 >> 3) + quad;   // 16 B chunk index within row
        bf16x8 a[4], b[4];
#pragma unroll
        for (int i = 0; i < 4; ++i)
            a[i] = *frag_ptr(As, wm * 64 + i * 16 + l16, c);
#pragma unroll
        for (int j = 0; j < 4; ++j)
            b[j] = *frag_ptr(Bs, wn * 64 + j * 16 + l16, c);
#pragma unroll
        for (int i = 0; i < 4; ++i)
#pragma unroll
            for (int j = 0; j < 4; ++j)
                acc[i][j] = __builtin_amdgcn_mfma_f32_16x16x32_bf16(
                    b[j], a[i], acc[i][j], 0, 0, 0);   // swapped: D[chan][node]
    }
}

__device__ __forceinline__ void mfma_tile_h(
    const unsigned short* __restrict__ Hs, const unsigned short* __restrict__ Bs,
    int kbc, int wm, int wn, int l16, int quad, f32x4 acc[4][4])
{
#pragma unroll
    for (int k0 = 0; k0 < 64; k0 += 32) {
        const int c = (k0 >> 3) + quad;
        bf16x8 a[4], b[4];
#pragma unroll
        for (int i = 0; i < 4; ++i)
            a[i] = *hfrag_ptr(Hs, wm * 64 + i * 16 + l16, kbc, c);
#pragma unroll
        for (int j = 0; j < 4; ++j)
            b[j] = *frag_ptr(Bs, wn * 64 + j * 16 + l16, c);
#pragma unroll
        for (int i = 0; i < 4; ++i)
#pragma unroll
            for (int j = 0; j < 4; ++j)
                acc[i][j] = __builtin_amdgcn_mfma_f32_16x16x32_bf16(
                    b[j], a[i], acc[i][j], 0, 0, 0);
    }
}

__global__ __launch_bounds__(512) void gemm_fused(
    const unsigned short* __restrict__ A1, const unsigned short* __restrict__ B1,
    const float* __restrict__ b1l, const unsigned short* __restrict__ W2cat,
    unsigned char* __restrict__ pb8, unsigned short* __restrict__ hrb)
{
    __shared__ unsigned short As[128 * 64];    // 16 KB
    __shared__ unsigned short Bs[256 * 64];    // 32 KB (phase 1: B1; phase 2: W2cat)
    __shared__ unsigned short Hs[128 * 256];   // 64 KB h-tile
    const int tid = threadIdx.x;
    const int wid = tid >> 6, lane = tid & 63;
    const int wm = wid & 1, wn = wid >> 1;     // 2M x 4N
    const int l16 = lane & 15, quad = lane >> 4;
    const int rowBase = blockIdx.x * 128;

    f32x4 z = {0.f, 0.f, 0.f, 0.f};
    f32x4 acc[4][4];
#pragma unroll
    for (int i = 0; i < 4; ++i)
#pragma unroll
        for (int j = 0; j < 4; ++j) acc[i][j] = z;

    // ---- phase 1: h = relu([mean|x] @ [W1l|W1r]^T + b1l), K=256 ----
#pragma unroll
    for (int kb = 0; kb < 256; kb += 64) {
        __syncthreads();
        stage8<2>(A1, 256, rowBase, N_NODES, kb, As, tid);
        stage8<4>(B1, 256, 0, HID_CH, kb, Bs, tid);
        __syncthreads();   // drains vmcnt(0): DMA complete before reads
        mfma_tile(As, Bs, wm, wn, l16, quad, acc);
    }

    // h-tile -> Hs (bf16, swizzled). Identical rounding to the old hb path.
#pragma unroll
    for (int i = 0; i < 4; ++i) {
        const int rr = wm * 64 + i * 16 + l16;          // row within tile
#pragma unroll
        for (int j = 0; j < 4; ++j) {
            const int colBase = wn * 64 + j * 16 + quad * 4;
            float4 bv = *reinterpret_cast<const float4*>(b1l + colBase);
            alignas(8) unsigned short t[4];
            t[0] = f32_bf16_rne(fmaxf(acc[i][j][0] + bv.x, 0.0f));
            t[1] = f32_bf16_rne(fmaxf(acc[i][j][1] + bv.y, 0.0f));
            t[2] = f32_bf16_rne(fmaxf(acc[i][j][2] + bv.z, 0.0f));
            t[3] = f32_bf16_rne(fmaxf(acc[i][j][3] + bv.w, 0.0f));
            const int grp  = colBase >> 6;              // 8-chunk group (= wn)
            const int lc   = (colBase >> 3) & 7;        // local chunk
            const int half = (colBase >> 2) & 1;        // 8 B half of 16 B chunk
            unsigned short* hp = Hs + rr * 256 +
                (((grp << 3) + (lc ^ (rr & 7))) << 3) + half * 4;
            *reinterpret_cast<uint2*>(hp) = *reinterpret_cast<const uint2*>(t);
        }
    }

    // ---- phase 2: [p | hr] = h @ W2cat^T, K=256, A from Hs ----
#pragma unroll
    for (int i = 0; i < 4; ++i)
#pragma unroll
        for (int j = 0; j < 4; ++j) acc[i][j] = z;

#pragma unroll
    for (int kb = 0; kb < HID_CH; kb += 64) {
        __syncthreads();   // Hs writes visible + phase-1 Bs reads done
        stage8<4>(W2cat, HID_CH, 0, 256, kb, Bs, tid);
        __syncthreads();
        mfma_tile_h(Hs, Bs, kb >> 3, wm, wn, l16, quad, acc);
    }

    if (wn < 2) {       // cols 0..127 -> fp8 payload p
#pragma unroll
        for (int i = 0; i < 4; ++i) {
            int m = rowBase + wm * 64 + i * 16 + l16;
            if (m >= N_NODES) continue;
#pragma unroll
            for (int j = 0; j < 4; ++j) {
                int col = wn * 64 + j * 16 + quad * 4;
                unsigned u = __builtin_amdgcn_cvt_pk_fp8_f32(
                    acc[i][j][0], acc[i][j][1], 0, false);
                u = __builtin_amdgcn_cvt_pk_fp8_f32(
                    acc[i][j][2], acc[i][j][3], u, true);
                *reinterpret_cast<unsigned*>(pb8 + (size_t)m * OUT_CH + col) = u;
            }
        }
    } else {            // cols 128..255 -> bf16 hr (bias deferred to agg2)
#pragma unroll
        for (int i = 0; i < 4; ++i) {
            int m = rowBase + wm * 64 + i * 16 + l16;
            if (m >= N_NODES) continue;
#pragma unroll
            for (int j = 0; j < 4; ++j) {
                int col = wn * 64 + j * 16 + quad * 4 - 128;
                alignas(8) unsigned short t[4];
                t[0] = f32_bf16_rne(acc[i][j][0]);
                t[1] = f32_bf16_rne(acc[i][j][1]);
                t[2] = f32_bf16_rne(acc[i][j][2]);
                t[3] = f32_bf16_rne(acc[i][j][3]);
                *reinterpret_cast<uint2*>(hrb + (size_t)m * OUT_CH + col) =
                    *reinterpret_cast<const uint2*>(t);
            }
        }
    }
}

extern "C" void kernel_launch(void* const* d_in, const int* in_sizes, int n_in,
                              void* d_out, int out_size, void* d_ws, size_t ws_size,
                              hipStream_t stream)
{
    const float* x   = (const float*)d_in[0];
    const int*   ei  = (const int*)d_in[1];
    const float* W1l = (const float*)d_in[2];
    const float* b1l = (const float*)d_in[3];
    const float* W1r = (const float*)d_in[4];
    const float* W2l = (const float*)d_in[5];
    const float* b2l = (const float*)d_in[6];
    const float* W2r = (const float*)d_in[7];

    const int E = in_sizes[1] / 2;
    const int* src = ei;
    const int* dst = ei + E;

    char* ws = (char*)d_ws;
    size_t off = 0;
    auto alloc = [&](size_t bytes) {
        void* p = ws + off;
        off += (bytes + 255) & ~(size_t)255;
        return p;
    };
    unsigned short* A1     = (unsigned short*)alloc((size_t)N_NODES * 256 * 2);
    unsigned char*  xb8    = (unsigned char*)alloc((size_t)N_NODES * IN_CH);
    unsigned char*  pb8    = (unsigned char*)alloc((size_t)N_NODES * OUT_CH);
    unsigned short* hrb    = (unsigned short*)alloc((size_t)N_NODES * OUT_CH * 2);
    unsigned short* B1     = (unsigned short*)alloc((size_t)HID_CH * 256 * 2);
    unsigned short* W2cat  = (unsigned short*)alloc((size_t)256 * HID_CH * 2);
    int* counts = (int*)alloc((size_t)NBNW * 4);
    int* S      = (int*)alloc((size_t)(NBNW + 1) * 4);
    int* pairs  = (int*)alloc((size_t)E * 4);
    int* rowptr = (int*)alloc((size_t)(N_NODES + 1) * 4);
    int* colidx = (int*)alloc((size_t)E * 4);
    float* out = (float*)d_out;

    const int chunk = (E + NWG - 1) / NWG;

    prep_kernel<<<NWG + XBLK + WBLK, 256, 0, stream>>>(
        src, dst, counts, E, chunk, x, A1, xb8,
        W1l, W1r, W2l, W2r, B1, W2cat);
    scan_kernel<<<NB, 256, 0, stream>>>(counts, S);
    bscatter_kernel<<<NWG, 256, 0, stream>>>(src, dst, S, pairs, E, chunk);
    bsort_kernel<<<NB, 256, 0, stream>>>(pairs, S, rowptr, colidx);

    const int aggBlocks = (N_NODES + 15) / 16;   // 3125
    const int mBlocks = (N_NODES + 127) / 128;   // 391

    agg1_kernel<<<aggBlocks, 256, 0, stream>>>(xb8, rowptr, colidx, A1);
    gemm_fused<<<mBlocks, 512, 0, stream>>>(A1, B1, b1l, W2cat, pb8, hrb);
    agg2_kernel<<<aggBlocks, 256, 0, stream>>>(pb8, rowptr, colidx, hrb, b2l, out);
}